// Round 1
// baseline (2459.142 us; speedup 1.0000x reference)
//
#include <hip/hip_runtime.h>
#include <math.h>

// ---------------------------------------------------------------------------
// DeepGT: 4-layer graph transformer (TransformerConv heads=1) on MI355X.
// Round 0: correctness-first fp32. CSR-by-dst build + online-softmax
// per-node-wave attention (no float atomics), register-blocked fp32 GEMM.
// ---------------------------------------------------------------------------

#define HD 128            // hidden dim
#define ODIM 40

// ---------------- CSR build ----------------

__global__ __launch_bounds__(256) void k_zero(int* __restrict__ p, int n) {
  int i = blockIdx.x * 256 + threadIdx.x;
  if (i < n) p[i] = 0;
}

__global__ __launch_bounds__(256) void k_hist(const int* __restrict__ dst, int E, int* __restrict__ deg) {
  int e = blockIdx.x * 256 + threadIdx.x;
  if (e < E) atomicAdd(&deg[dst[e]], 1);
}

// per-chunk (256 nodes) sums
__global__ __launch_bounds__(256) void k_scan_a(const int* __restrict__ deg, int N, int NCH,
                                                int* __restrict__ csum) {
  int c = blockIdx.x * 256 + threadIdx.x;
  if (c >= NCH) return;
  int base = c * 256;
  int lim = min(256, N - base);
  int s = 0;
  for (int i = 0; i < lim; ++i) s += deg[base + i];
  csum[c] = s;
}

// exclusive scan of up to 512 chunk sums, single block
__global__ __launch_bounds__(512) void k_scan_b(const int* __restrict__ csum, int NCH,
                                                int* __restrict__ coff) {
  __shared__ int buf[512];
  int t = threadIdx.x;
  int v = (t < NCH) ? csum[t] : 0;
  buf[t] = v;
  __syncthreads();
  for (int off = 1; off < 512; off <<= 1) {
    int x = (t >= off) ? buf[t - off] : 0;
    __syncthreads();
    buf[t] += x;
    __syncthreads();
  }
  if (t < NCH) coff[t] = buf[t] - v;  // exclusive prefix
}

// per-chunk exclusive scan -> rowptr, wp
__global__ __launch_bounds__(256) void k_scan_c(const int* __restrict__ deg, const int* __restrict__ coff,
                                                int N, int E, int* __restrict__ rowptr,
                                                int* __restrict__ wp) {
  __shared__ int buf[256];
  int c = blockIdx.x, t = threadIdx.x;
  int i = c * 256 + t;
  int v = (i < N) ? deg[i] : 0;
  buf[t] = v;
  __syncthreads();
  for (int off = 1; off < 256; off <<= 1) {
    int x = (t >= off) ? buf[t - off] : 0;
    __syncthreads();
    buf[t] += x;
    __syncthreads();
  }
  if (i < N) {
    int rp = coff[c] + buf[t] - v;
    rowptr[i] = rp;
    wp[i] = rp;
  }
  if (c == 0 && t == 0) rowptr[N] = E;
}

__global__ __launch_bounds__(256) void k_fill(const int* __restrict__ src, const int* __restrict__ dst,
                                              int E, int* __restrict__ wp, int* __restrict__ colsrc) {
  int e = blockIdx.x * 256 + threadIdx.x;
  if (e < E) {
    int p = atomicAdd(&wp[dst[e]], 1);
    colsrc[p] = src[e];
  }
}

// ---------------- GEMM: out[N,128] = A[N,128] @ W[128,128] + bias ----------------
// Block: 256 threads, 64 rows x 128 cols. Thread: 8 rows x 4 cols acc.
// Safe for in-place (out == A): A staged fully through LDS before any store.

__global__ __launch_bounds__(256) void k_gemm128(const float* A, const float* __restrict__ W,
                                                 const float* __restrict__ bias, float* out, int nrows) {
  __shared__ float As[64 * HD];
  int row0 = blockIdx.x * 64;
  int t = threadIdx.x;
  int maxf4 = (min(64, nrows - row0)) * (HD / 4);
  const float4* A4 = (const float4*)(A + (size_t)row0 * HD);
  float4* As4 = (float4*)As;
#pragma unroll
  for (int i = 0; i < 8; ++i) {
    int idx = t + i * 256;
    float4 val = make_float4(0.f, 0.f, 0.f, 0.f);
    if (idx < maxf4) val = A4[idx];
    As4[idx] = val;
  }
  __syncthreads();

  int tx = t & 31;   // col group: cols 4*tx .. 4*tx+3
  int ty = t >> 5;   // row group: rows 8*ty .. 8*ty+7
  float acc[8][4];
#pragma unroll
  for (int r = 0; r < 8; ++r) acc[r][0] = acc[r][1] = acc[r][2] = acc[r][3] = 0.f;

  const float* Arow = As + (ty * 8) * HD;
#pragma unroll 4
  for (int kk = 0; kk < HD; ++kk) {
    float4 w4 = *(const float4*)(W + kk * HD + tx * 4);
#pragma unroll
    for (int r = 0; r < 8; ++r) {
      float a = Arow[r * HD + kk];
      acc[r][0] = fmaf(a, w4.x, acc[r][0]);
      acc[r][1] = fmaf(a, w4.y, acc[r][1]);
      acc[r][2] = fmaf(a, w4.z, acc[r][2]);
      acc[r][3] = fmaf(a, w4.w, acc[r][3]);
    }
  }

  float4 b4 = *(const float4*)(bias + tx * 4);
#pragma unroll
  for (int r = 0; r < 8; ++r) {
    int row = row0 + ty * 8 + r;
    if (row < nrows) {
      float4 o;
      o.x = acc[r][0] + b4.x;
      o.y = acc[r][1] + b4.y;
      o.z = acc[r][2] + b4.z;
      o.w = acc[r][3] + b4.w;
      *(float4*)(out + (size_t)row * HD + tx * 4) = o;
    }
  }
}

// ---------------- Attention + aggregate + skip + ELU (one wave per node) ---------
// Online softmax over the node's incoming edges; coalesced 512B row gathers.
// s (skip projection) may alias h_out: each wave reads/writes only its own row.

__global__ __launch_bounds__(256) void k_attn(const float* __restrict__ q, const float* __restrict__ k,
                                              const float* __restrict__ v, const float* s,
                                              const int* __restrict__ rowptr, const int* __restrict__ colsrc,
                                              float* h_out, int n, int do_elu) {
  int wid = blockIdx.x * 4 + (threadIdx.x >> 6);
  int lane = threadIdx.x & 63;
  if (wid >= n) return;
  const float scale = 0.088388347648318447f;  // 1/sqrt(128)

  float2 qv = *(const float2*)(q + (size_t)wid * HD + lane * 2);
  int e0 = rowptr[wid], e1 = rowptr[wid + 1];

  float M = -INFINITY, S = 0.f;
  float a0 = 0.f, a1 = 0.f;

  for (int e = e0; e < e1; ++e) {
    int j = colsrc[e];
    float2 kv = *(const float2*)(k + (size_t)j * HD + lane * 2);
    float part = qv.x * kv.x + qv.y * kv.y;
#pragma unroll
    for (int off = 32; off > 0; off >>= 1) part += __shfl_xor(part, off, 64);
    float logit = part * scale;
    float2 vv = *(const float2*)(v + (size_t)j * HD + lane * 2);
    float newM = fmaxf(M, logit);
    float f = __expf(M - newM);      // exp(-inf)=0 on first edge
    float w = __expf(logit - newM);
    S = S * f + w;
    a0 = a0 * f + w * vv.x;
    a1 = a1 * f + w * vv.y;
    M = newM;
  }

  float inv = (S > 0.f) ? 1.f / S : 0.f;  // deg==0 -> agg = 0 (matches reference guard)
  a0 *= inv;
  a1 *= inv;

  float2 sk = *(const float2*)(s + (size_t)wid * HD + lane * 2);
  float o0 = a0 + sk.x;
  float o1 = a1 + sk.y;
  if (do_elu) {
    o0 = (o0 > 0.f) ? o0 : (__expf(o0) - 1.f);
    o1 = (o1 > 0.f) ? o1 : (__expf(o1) - 1.f);
  }
  *(float2*)(h_out + (size_t)wid * HD + lane * 2) = make_float2(o0, o1);
}

// ---------------- Classifier + log_softmax (one wave per node) ----------------

__global__ __launch_bounds__(256) void k_fc_lsm(const float* __restrict__ h, const float* __restrict__ W,
                                                const float* __restrict__ b, float* __restrict__ out, int n) {
  int wid = blockIdx.x * 4 + (threadIdx.x >> 6);
  int lane = threadIdx.x & 63;
  if (wid >= n) return;
  const float* hrow = h + (size_t)wid * HD;

  float acc = 0.f;
  if (lane < ODIM) {
    for (int kk = 0; kk < HD; ++kk) acc = fmaf(hrow[kk], W[kk * ODIM + lane], acc);
    acc += b[lane];
  }
  float y = (lane < ODIM) ? acc : -INFINITY;
  float m = y;
#pragma unroll
  for (int off = 32; off > 0; off >>= 1) m = fmaxf(m, __shfl_xor(m, off, 64));
  float ex = (lane < ODIM) ? __expf(y - m) : 0.f;
  float sum = ex;
#pragma unroll
  for (int off = 32; off > 0; off >>= 1) sum += __shfl_xor(sum, off, 64);
  float lse = m + logf(sum);
  if (lane < ODIM) out[(size_t)wid * ODIM + lane] = acc - lse;
}

// ---------------- host ----------------

extern "C" void kernel_launch(void* const* d_in, const int* in_sizes, int n_in,
                              void* d_out, int out_size, void* d_ws, size_t ws_size,
                              hipStream_t stream) {
  const float* x    = (const float*)d_in[0];
  const int*   ei   = (const int*)d_in[1];
  const float* linW = (const float*)d_in[2];
  const float* linb = (const float*)d_in[3];
  const float* Wq   = (const float*)d_in[4];
  const float* bq   = (const float*)d_in[5];
  const float* Wk   = (const float*)d_in[6];
  const float* bk   = (const float*)d_in[7];
  const float* Wv   = (const float*)d_in[8];
  const float* bv   = (const float*)d_in[9];
  const float* Wsk  = (const float*)d_in[10];
  const float* bsk  = (const float*)d_in[11];
  const float* fcW  = (const float*)d_in[12];
  const float* fcb  = (const float*)d_in[13];
  float* out = (float*)d_out;

  const int N = in_sizes[0] / HD;
  const int E = in_sizes[1] / 2;
  const int* srcv = ei;       // edge_index[0] = message source
  const int* dstv = ei + E;   // edge_index[1] = aggregation target

  // workspace carve (256B aligned)
  size_t off = 0;
  char* base = (char*)d_ws;
  auto carve = [&](size_t bytes) -> void* {
    void* p = base + off;
    off = (off + bytes + 255) & ~(size_t)255;
    return p;
  };
  float* h  = (float*)carve((size_t)N * HD * 4);
  float* q  = (float*)carve((size_t)N * HD * 4);
  float* k  = (float*)carve((size_t)N * HD * 4);
  float* v  = (float*)carve((size_t)N * HD * 4);
  int* deg    = (int*)carve((size_t)N * 4);
  int* wp     = (int*)carve((size_t)N * 4);
  int* rowptr = (int*)carve((size_t)(N + 1) * 4);
  int* colsrc = (int*)carve((size_t)E * 4);
  int* csum   = (int*)carve(512 * 4);
  int* coff   = (int*)carve(512 * 4);
  (void)ws_size; (void)n_in; (void)out_size;

  const int NCH = (N + 255) / 256;         // chunks of 256 nodes (<=512 required; 391 here)
  dim3 blk(256);
  int eb = (E + 255) / 256;
  int nb = (N + 255) / 256;
  int gx = (N + 63) / 64;                  // GEMM row-tiles
  int wb = (N + 3) / 4;                    // wave-per-node blocks (4 waves/block)

  // ---- CSR by dst ----
  k_zero<<<nb, blk, 0, stream>>>(deg, N);
  k_hist<<<eb, blk, 0, stream>>>(dstv, E, deg);
  k_scan_a<<<(NCH + 255) / 256, blk, 0, stream>>>(deg, N, NCH, csum);
  k_scan_b<<<1, 512, 0, stream>>>(csum, NCH, coff);
  k_scan_c<<<NCH, blk, 0, stream>>>(deg, coff, N, E, rowptr, wp);
  k_fill<<<eb, blk, 0, stream>>>(srcv, dstv, E, wp, colsrc);

  // ---- input projection ----
  k_gemm128<<<gx, blk, 0, stream>>>(x, linW, linb, h, N);

  // ---- layers ----
  for (int l = 0; l < 4; ++l) {
    const float* wq = Wq + (size_t)l * HD * HD;
    const float* wk = Wk + (size_t)l * HD * HD;
    const float* wv = Wv + (size_t)l * HD * HD;
    const float* ws = Wsk + (size_t)l * HD * HD;
    k_gemm128<<<gx, blk, 0, stream>>>(h, wq, bq + l * HD, q, N);
    k_gemm128<<<gx, blk, 0, stream>>>(h, wk, bk + l * HD, k, N);
    k_gemm128<<<gx, blk, 0, stream>>>(h, wv, bv + l * HD, v, N);
    // skip projection in-place: h <- h @ Ws + bs (block stages rows via LDS first)
    k_gemm128<<<gx, blk, 0, stream>>>(h, ws, bsk + l * HD, h, N);
    // h <- agg + skip (s aliases h_out, row-private), ELU for l<3
    k_attn<<<wb, blk, 0, stream>>>(q, k, v, h, rowptr, colsrc, h, N, (l < 3) ? 1 : 0);
  }

  // ---- classifier + log_softmax ----
  k_fc_lsm<<<wb, blk, 0, stream>>>(h, fcW, fcb, out, N);
}

// Round 2
// 1593.580 us; speedup vs baseline: 1.5432x; 1.5432x over previous
//
#include <hip/hip_runtime.h>
#include <hip/hip_bf16.h>
#include <math.h>

// ---------------------------------------------------------------------------
// DeepGT round 1: bf16 MFMA fused-QKVS GEMM + bf16 half-wave-slot attention.
// ---------------------------------------------------------------------------

#define HD 128
#define ODIM 40
#define LDSA 136  // padded LDS row stride (bf16 elems): 128 + 8 -> 2-way-conflict-free

typedef __attribute__((ext_vector_type(8))) short short8;
typedef __attribute__((ext_vector_type(4))) float f4v;
typedef __attribute__((ext_vector_type(4))) unsigned short us4;
typedef __attribute__((ext_vector_type(8))) unsigned short us8;

static __device__ __forceinline__ float b2f(unsigned short u) {
  return __uint_as_float(((unsigned)u) << 16);
}
static __device__ __forceinline__ unsigned short f2b(float f) {
  __hip_bfloat16 h = __float2bfloat16(f);
  return __builtin_bit_cast(unsigned short, h);
}

// ---------------- CSR build ----------------

__global__ __launch_bounds__(256) void k_zero(int* __restrict__ p, int n) {
  int i = blockIdx.x * 256 + threadIdx.x;
  if (i < n) p[i] = 0;
}

__global__ __launch_bounds__(256) void k_hist(const int* __restrict__ dst, int E, int* __restrict__ deg) {
  int e = blockIdx.x * 256 + threadIdx.x;
  if (e < E) atomicAdd(&deg[dst[e]], 1);
}

__global__ __launch_bounds__(256) void k_scan_a(const int* __restrict__ deg, int N, int NCH,
                                                int* __restrict__ csum) {
  int c = blockIdx.x * 256 + threadIdx.x;
  if (c >= NCH) return;
  int base = c * 256;
  int lim = min(256, N - base);
  int s = 0;
  for (int i = 0; i < lim; ++i) s += deg[base + i];
  csum[c] = s;
}

__global__ __launch_bounds__(512) void k_scan_b(const int* __restrict__ csum, int NCH,
                                                int* __restrict__ coff) {
  __shared__ int buf[512];
  int t = threadIdx.x;
  int v = (t < NCH) ? csum[t] : 0;
  buf[t] = v;
  __syncthreads();
  for (int off = 1; off < 512; off <<= 1) {
    int x = (t >= off) ? buf[t - off] : 0;
    __syncthreads();
    buf[t] += x;
    __syncthreads();
  }
  if (t < NCH) coff[t] = buf[t] - v;
}

__global__ __launch_bounds__(256) void k_scan_c(const int* __restrict__ deg, const int* __restrict__ coff,
                                                int N, int E, int* __restrict__ rowptr,
                                                int* __restrict__ wp) {
  __shared__ int buf[256];
  int c = blockIdx.x, t = threadIdx.x;
  int i = c * 256 + t;
  int v = (i < N) ? deg[i] : 0;
  buf[t] = v;
  __syncthreads();
  for (int off = 1; off < 256; off <<= 1) {
    int x = (t >= off) ? buf[t - off] : 0;
    __syncthreads();
    buf[t] += x;
    __syncthreads();
  }
  if (i < N) {
    int rp = coff[c] + buf[t] - v;
    rowptr[i] = rp;
    wp[i] = rp;
  }
  if (c == 0 && t == 0) rowptr[N] = E;
}

__global__ __launch_bounds__(256) void k_fill(const int* __restrict__ src, const int* __restrict__ dst,
                                              int E, int* __restrict__ wp, int* __restrict__ colsrc) {
  int e = blockIdx.x * 256 + threadIdx.x;
  if (e < E) {
    int p = atomicAdd(&wp[dst[e]], 1);
    colsrc[p] = src[e];
  }
}

// ---------------- weight pack: fp32 [k][n] -> bf16 [n][k] ----------------
// Wp layout (bf16 elems): [0,16384) lin; [16384,278528) 4 layers x [512n][128k]
// (n: 0-127 q, 128-255 k, 256-383 v, 384-511 s); [278528,283648) fc [40n][128k].

__global__ __launch_bounds__(256) void k_pack(const float* __restrict__ linW,
                                              const float* __restrict__ Wq, const float* __restrict__ Wk,
                                              const float* __restrict__ Wv, const float* __restrict__ Ws,
                                              const float* __restrict__ fcW,
                                              unsigned short* __restrict__ Wp) {
  int idx = blockIdx.x * 256 + threadIdx.x;
  float val;
  if (idx < 16384) {
    int n = idx >> 7, kk = idx & 127;
    val = linW[kk * 128 + n];
  } else if (idx < 278528) {
    int t = idx - 16384;
    int l = t >> 16, r = t & 65535;
    int n = r >> 7, kk = r & 127;
    int which = n >> 7, nn = n & 127;
    const float* W = (which == 0) ? Wq : (which == 1) ? Wk : (which == 2) ? Wv : Ws;
    val = W[(size_t)l * 16384 + kk * 128 + nn];
  } else if (idx < 283648) {
    int t = idx - 278528;
    int n = t >> 7, kk = t & 127;
    val = fcW[kk * ODIM + n];
  } else {
    return;
  }
  Wp[idx] = f2b(val);
}

// ---------------- GEMM lin: hb[N,128] = bf16( x[N,128] @ linW + linb ) ----------------
// block: 256 thr = 4 waves, 32 rows; wave: 16 rows x 64 cols (4 MFMA col tiles)

__global__ __launch_bounds__(256) void k_gemm_lin(const float* __restrict__ x,
                                                  const unsigned short* __restrict__ wl,  // [128n][128k]
                                                  const float* __restrict__ bias,
                                                  unsigned short* __restrict__ hb, int N) {
  __shared__ unsigned short As[32 * LDSA];
  int t = threadIdx.x;
  int rowbase = blockIdx.x * 32;
#pragma unroll
  for (int i = 0; i < 2; ++i) {
    int c = t + i * 256;       // chunk of 8 floats
    int r = c >> 4, c8 = c & 15;
    int gr = rowbase + r;
    if (gr >= N) gr = N - 1;
    const float4* xp = (const float4*)(x + (size_t)gr * 128 + c8 * 8);
    float4 u0 = xp[0], u1 = xp[1];
    us8 o;
    o[0] = f2b(u0.x); o[1] = f2b(u0.y); o[2] = f2b(u0.z); o[3] = f2b(u0.w);
    o[4] = f2b(u1.x); o[5] = f2b(u1.y); o[6] = f2b(u1.z); o[7] = f2b(u1.w);
    *(us8*)(As + r * LDSA + c8 * 8) = o;
  }
  __syncthreads();

  int lane = t & 63, w = t >> 6;
  int rh = (w & 1) * 16;
  int ch = (w >> 1) * 64;
  int lm = lane & 15, lq = lane >> 4;

  short8 a[4];
#pragma unroll
  for (int ks = 0; ks < 4; ++ks)
    a[ks] = *(const short8*)(As + (rh + lm) * LDSA + ks * 32 + lq * 8);

  f4v acc[4];
#pragma unroll
  for (int ct = 0; ct < 4; ++ct) acc[ct] = (f4v){0.f, 0.f, 0.f, 0.f};

#pragma unroll
  for (int ct = 0; ct < 4; ++ct) {
    const short8* bp = (const short8*)(wl + ((size_t)(ch + ct * 16 + lm)) * 128 + lq * 8);
    short8 b0 = bp[0], b1 = bp[4], b2 = bp[8], b3 = bp[12];
    acc[ct] = __builtin_amdgcn_mfma_f32_16x16x32_bf16(a[0], b0, acc[ct], 0, 0, 0);
    acc[ct] = __builtin_amdgcn_mfma_f32_16x16x32_bf16(a[1], b1, acc[ct], 0, 0, 0);
    acc[ct] = __builtin_amdgcn_mfma_f32_16x16x32_bf16(a[2], b2, acc[ct], 0, 0, 0);
    acc[ct] = __builtin_amdgcn_mfma_f32_16x16x32_bf16(a[3], b3, acc[ct], 0, 0, 0);
  }

#pragma unroll
  for (int ct = 0; ct < 4; ++ct) {
    int c = ch + ct * 16 + lm;
    float bv = bias[c];
#pragma unroll
    for (int r = 0; r < 4; ++r) {
      int row = rowbase + rh + lq * 4 + r;
      if (row < N) hb[(size_t)row * 128 + c] = f2b(acc[ct][r] + bv);
    }
  }
}

// ---------------- GEMM fused qkvs: [q|k|v|s] = hb @ [Wq|Wk|Wv|Ws] + bias ----------------
// block: 256 thr = 4 waves, 32 rows x 512 cols; wave: 16 rows x 256 cols (16 col tiles)

__global__ __launch_bounds__(256) void k_gemm_qkvs(const unsigned short* __restrict__ hb,
                                                   const unsigned short* __restrict__ wl,  // [512n][128k]
                                                   const float* __restrict__ bq, const float* __restrict__ bk,
                                                   const float* __restrict__ bv, const float* __restrict__ bs,
                                                   unsigned short* __restrict__ q, unsigned short* __restrict__ k,
                                                   unsigned short* __restrict__ v, float* __restrict__ s, int N) {
  __shared__ unsigned short As[32 * LDSA];
  int t = threadIdx.x;
  int rowbase = blockIdx.x * 32;
#pragma unroll
  for (int i = 0; i < 2; ++i) {
    int c = t + i * 256;
    int r = c >> 4, c8 = c & 15;
    int gr = rowbase + r;
    if (gr >= N) gr = N - 1;
    us8 val = *(const us8*)(hb + (size_t)gr * 128 + c8 * 8);
    *(us8*)(As + r * LDSA + c8 * 8) = val;
  }
  __syncthreads();

  int lane = t & 63, w = t >> 6;
  int rh = (w & 1) * 16;
  int ch = (w >> 1) * 256;
  int lm = lane & 15, lq = lane >> 4;

  short8 a[4];
#pragma unroll
  for (int ks = 0; ks < 4; ++ks)
    a[ks] = *(const short8*)(As + (rh + lm) * LDSA + ks * 32 + lq * 8);

  f4v acc[16];
#pragma unroll
  for (int ct = 0; ct < 16; ++ct) acc[ct] = (f4v){0.f, 0.f, 0.f, 0.f};

#pragma unroll
  for (int ct = 0; ct < 16; ++ct) {
    const short8* bp = (const short8*)(wl + ((size_t)(ch + ct * 16 + lm)) * 128 + lq * 8);
    short8 b0 = bp[0], b1 = bp[4], b2 = bp[8], b3 = bp[12];
    acc[ct] = __builtin_amdgcn_mfma_f32_16x16x32_bf16(a[0], b0, acc[ct], 0, 0, 0);
    acc[ct] = __builtin_amdgcn_mfma_f32_16x16x32_bf16(a[1], b1, acc[ct], 0, 0, 0);
    acc[ct] = __builtin_amdgcn_mfma_f32_16x16x32_bf16(a[2], b2, acc[ct], 0, 0, 0);
    acc[ct] = __builtin_amdgcn_mfma_f32_16x16x32_bf16(a[3], b3, acc[ct], 0, 0, 0);
  }

#pragma unroll
  for (int ct = 0; ct < 16; ++ct) {
    int c = ch + ct * 16 + lm;
    int which = c >> 7, cc = c & 127;
    const float* bsel = (which == 0) ? bq : (which == 1) ? bk : (which == 2) ? bv : bs;
    float bias = bsel[cc];
    unsigned short* obf = (which == 0) ? q : (which == 1) ? k : v;
#pragma unroll
    for (int r = 0; r < 4; ++r) {
      int row = rowbase + rh + lq * 4 + r;
      if (row < N) {
        float val = acc[ct][r] + bias;
        if (which < 3) obf[(size_t)row * 128 + cc] = f2b(val);
        else s[(size_t)row * 128 + cc] = val;
      }
    }
  }
}

// ---------------- attention: one wave/node, two 32-lane edge slots ----------------
// lane holds 4 dims; slot = lane>>5 processes its half of the edge list (batch 2),
// online softmax per slot, slots merged by shfl_xor(32) at the end.

__global__ __launch_bounds__(256) void k_attn2(const unsigned short* __restrict__ q,
                                               const unsigned short* __restrict__ kb,
                                               const unsigned short* __restrict__ vb,
                                               const float* __restrict__ s,
                                               const int* __restrict__ rowptr, const int* __restrict__ colsrc,
                                               unsigned short* __restrict__ hb, int n, int do_elu) {
  int wid = blockIdx.x * 4 + (threadIdx.x >> 6);
  if (wid >= n) return;
  int lane = threadIdx.x & 63;
  int half = lane >> 5;
  int d0 = (lane & 31) * 4;
  const float scale = 0.08838834764831844f;  // 1/sqrt(128)

  us4 qu = *(const us4*)(q + (size_t)wid * 128 + d0);
  float q0 = b2f(qu[0]), q1 = b2f(qu[1]), q2 = b2f(qu[2]), q3 = b2f(qu[3]);

  int e0 = rowptr[wid], e1 = rowptr[wid + 1];
  int mid = e0 + ((e1 - e0 + 1) >> 1);
  int lo = half ? mid : e0;
  int hi = half ? e1 : mid;

  float M = -INFINITY, S = 0.f;
  float a0 = 0.f, a1 = 0.f, a2 = 0.f, a3 = 0.f;

  int e = lo;
  for (; e + 1 < hi; e += 2) {
    int j0 = colsrc[e], j1 = colsrc[e + 1];
    us4 k0 = *(const us4*)(kb + (size_t)j0 * 128 + d0);
    us4 k1 = *(const us4*)(kb + (size_t)j1 * 128 + d0);
    us4 v0 = *(const us4*)(vb + (size_t)j0 * 128 + d0);
    us4 v1 = *(const us4*)(vb + (size_t)j1 * 128 + d0);
    float p0 = q0 * b2f(k0[0]) + q1 * b2f(k0[1]) + q2 * b2f(k0[2]) + q3 * b2f(k0[3]);
    float p1 = q0 * b2f(k1[0]) + q1 * b2f(k1[1]) + q2 * b2f(k1[2]) + q3 * b2f(k1[3]);
#pragma unroll
    for (int off = 1; off <= 16; off <<= 1) {
      p0 += __shfl_xor(p0, off, 64);
      p1 += __shfl_xor(p1, off, 64);
    }
    float l0 = p0 * scale, l1 = p1 * scale;
    float newM = fmaxf(M, fmaxf(l0, l1));
    float f = __expf(M - newM);
    float w0 = __expf(l0 - newM), w1 = __expf(l1 - newM);
    S = S * f + w0 + w1;
    a0 = a0 * f + w0 * b2f(v0[0]) + w1 * b2f(v1[0]);
    a1 = a1 * f + w0 * b2f(v0[1]) + w1 * b2f(v1[1]);
    a2 = a2 * f + w0 * b2f(v0[2]) + w1 * b2f(v1[2]);
    a3 = a3 * f + w0 * b2f(v0[3]) + w1 * b2f(v1[3]);
    M = newM;
  }
  if (e < hi) {
    int j0 = colsrc[e];
    us4 k0 = *(const us4*)(kb + (size_t)j0 * 128 + d0);
    us4 v0 = *(const us4*)(vb + (size_t)j0 * 128 + d0);
    float p0 = q0 * b2f(k0[0]) + q1 * b2f(k0[1]) + q2 * b2f(k0[2]) + q3 * b2f(k0[3]);
#pragma unroll
    for (int off = 1; off <= 16; off <<= 1) p0 += __shfl_xor(p0, off, 64);
    float l0 = p0 * scale;
    float newM = fmaxf(M, l0);
    float f = __expf(M - newM);
    float w0 = __expf(l0 - newM);
    S = S * f + w0;
    a0 = a0 * f + w0 * b2f(v0[0]);
    a1 = a1 * f + w0 * b2f(v0[1]);
    a2 = a2 * f + w0 * b2f(v0[2]);
    a3 = a3 * f + w0 * b2f(v0[3]);
    M = newM;
  }

  // merge the two slots
  float Mo = __shfl_xor(M, 32, 64);
  float So = __shfl_xor(S, 32, 64);
  float b0 = __shfl_xor(a0, 32, 64);
  float b1 = __shfl_xor(a1, 32, 64);
  float b2 = __shfl_xor(a2, 32, 64);
  float b3 = __shfl_xor(a3, 32, 64);
  float newM = fmaxf(M, Mo);
  float fs, fo;
  if (newM == -INFINITY) {
    fs = 0.f; fo = 0.f;        // isolated node: avoid (-inf)-(-inf) NaN
  } else {
    fs = __expf(M - newM);
    fo = __expf(Mo - newM);
  }
  S = S * fs + So * fo;
  a0 = a0 * fs + b0 * fo;
  a1 = a1 * fs + b1 * fo;
  a2 = a2 * fs + b2 * fo;
  a3 = a3 * fs + b3 * fo;
  float inv = (S > 0.f) ? 1.f / S : 0.f;

  float4 sk = *(const float4*)(s + (size_t)wid * 128 + d0);
  float o0 = a0 * inv + sk.x;
  float o1 = a1 * inv + sk.y;
  float o2 = a2 * inv + sk.z;
  float o3 = a3 * inv + sk.w;
  if (do_elu) {
    o0 = (o0 > 0.f) ? o0 : (__expf(o0) - 1.f);
    o1 = (o1 > 0.f) ? o1 : (__expf(o1) - 1.f);
    o2 = (o2 > 0.f) ? o2 : (__expf(o2) - 1.f);
    o3 = (o3 > 0.f) ? o3 : (__expf(o3) - 1.f);
  }
  if (half == 0) {
    us4 ov;
    ov[0] = f2b(o0); ov[1] = f2b(o1); ov[2] = f2b(o2); ov[3] = f2b(o3);
    *(us4*)(hb + (size_t)wid * 128 + d0) = ov;
  }
}

// ---------------- classifier + log_softmax (one wave per node) ----------------

__global__ __launch_bounds__(256) void k_fc_lsm(const unsigned short* __restrict__ hb,
                                                const unsigned short* __restrict__ fcp,  // [40n][128k]
                                                const float* __restrict__ fcb,
                                                float* __restrict__ out, int n) {
  int wid = blockIdx.x * 4 + (threadIdx.x >> 6);
  if (wid >= n) return;
  int lane = threadIdx.x & 63;
  float acc = 0.f;
  if (lane < ODIM) {
    const us8* hrow = (const us8*)(hb + (size_t)wid * 128);
    const us8* wr = (const us8*)(fcp + lane * 128);
#pragma unroll
    for (int c = 0; c < 16; ++c) {
      us8 hv = hrow[c], wv = wr[c];
#pragma unroll
      for (int i = 0; i < 8; ++i) acc = fmaf(b2f(hv[i]), b2f(wv[i]), acc);
    }
    acc += fcb[lane];
  }
  float y = (lane < ODIM) ? acc : -INFINITY;
  float m = y;
#pragma unroll
  for (int off = 32; off > 0; off >>= 1) m = fmaxf(m, __shfl_xor(m, off, 64));
  float ex = (lane < ODIM) ? __expf(y - m) : 0.f;
  float sum = ex;
#pragma unroll
  for (int off = 32; off > 0; off >>= 1) sum += __shfl_xor(sum, off, 64);
  float lse = m + logf(sum);
  if (lane < ODIM) out[(size_t)wid * ODIM + lane] = acc - lse;
}

// ---------------- host ----------------

extern "C" void kernel_launch(void* const* d_in, const int* in_sizes, int n_in,
                              void* d_out, int out_size, void* d_ws, size_t ws_size,
                              hipStream_t stream) {
  const float* x    = (const float*)d_in[0];
  const int*   ei   = (const int*)d_in[1];
  const float* linW = (const float*)d_in[2];
  const float* linb = (const float*)d_in[3];
  const float* Wq   = (const float*)d_in[4];
  const float* bq   = (const float*)d_in[5];
  const float* Wk   = (const float*)d_in[6];
  const float* bk   = (const float*)d_in[7];
  const float* Wv   = (const float*)d_in[8];
  const float* bv   = (const float*)d_in[9];
  const float* Wsk  = (const float*)d_in[10];
  const float* bsk  = (const float*)d_in[11];
  const float* fcW  = (const float*)d_in[12];
  const float* fcb  = (const float*)d_in[13];
  float* out = (float*)d_out;

  const int N = in_sizes[0] / HD;
  const int E = in_sizes[1] / 2;
  const int* srcv = ei;
  const int* dstv = ei + E;

  size_t off = 0;
  char* base = (char*)d_ws;
  auto carve = [&](size_t bytes) -> void* {
    void* p = base + off;
    off = (off + bytes + 255) & ~(size_t)255;
    return p;
  };
  unsigned short* Wp = (unsigned short*)carve(283648 * 2);
  unsigned short* hb = (unsigned short*)carve((size_t)N * HD * 2);
  unsigned short* qb = (unsigned short*)carve((size_t)N * HD * 2);
  unsigned short* kbuf = (unsigned short*)carve((size_t)N * HD * 2);
  unsigned short* vbuf = (unsigned short*)carve((size_t)N * HD * 2);
  float* sbuf = (float*)carve((size_t)N * HD * 4);
  int* deg    = (int*)carve((size_t)N * 4);
  int* wp     = (int*)carve((size_t)N * 4);
  int* rowptr = (int*)carve((size_t)(N + 1) * 4);
  int* colsrc = (int*)carve((size_t)E * 4);
  int* csum   = (int*)carve(512 * 4);
  int* coff   = (int*)carve(512 * 4);
  (void)ws_size; (void)n_in; (void)out_size;

  const int NCH = (N + 255) / 256;
  dim3 blk(256);
  int eb = (E + 255) / 256;
  int nb = (N + 255) / 256;
  int gx = (N + 31) / 32;
  int wb = (N + 3) / 4;

  // CSR by dst
  k_zero<<<nb, blk, 0, stream>>>(deg, N);
  k_hist<<<eb, blk, 0, stream>>>(dstv, E, deg);
  k_scan_a<<<(NCH + 255) / 256, blk, 0, stream>>>(deg, N, NCH, csum);
  k_scan_b<<<1, 512, 0, stream>>>(csum, NCH, coff);
  k_scan_c<<<NCH, blk, 0, stream>>>(deg, coff, N, E, rowptr, wp);
  k_fill<<<eb, blk, 0, stream>>>(srcv, dstv, E, wp, colsrc);

  // weight pack
  k_pack<<<(283648 + 255) / 256, blk, 0, stream>>>(linW, Wq, Wk, Wv, Wsk, fcW, Wp);

  // input projection
  k_gemm_lin<<<gx, blk, 0, stream>>>(x, Wp, linb, hb, N);

  // layers
  for (int l = 0; l < 4; ++l) {
    const unsigned short* wl = Wp + 16384 + (size_t)l * 65536;
    k_gemm_qkvs<<<gx, blk, 0, stream>>>(hb, wl, bq + l * HD, bk + l * HD, bv + l * HD, bsk + l * HD,
                                        qb, kbuf, vbuf, sbuf, N);
    k_attn2<<<wb, blk, 0, stream>>>(qb, kbuf, vbuf, sbuf, rowptr, colsrc, hb, N, (l < 3) ? 1 : 0);
  }

  // classifier + log_softmax
  k_fc_lsm<<<wb, blk, 0, stream>>>(hb, Wp + 278528, fcb, out, N);
}

// Round 3
// 1441.305 us; speedup vs baseline: 1.7062x; 1.1057x over previous
//
#include <hip/hip_runtime.h>
#include <hip/hip_bf16.h>
#include <math.h>

// ---------------------------------------------------------------------------
// DeepGT round 2: round-1 structure + MFMA fused classifier/log_softmax
// (k_fc_lsm was 189 us VALU-bound scalar-bf16; now 12 MFMA/block + shuffle LSM).
// ---------------------------------------------------------------------------

#define HD 128
#define ODIM 40
#define LDSA 136  // padded LDS row stride (bf16 elems)

typedef __attribute__((ext_vector_type(8))) short short8;
typedef __attribute__((ext_vector_type(4))) float f4v;
typedef __attribute__((ext_vector_type(4))) unsigned short us4;
typedef __attribute__((ext_vector_type(8))) unsigned short us8;

static __device__ __forceinline__ float b2f(unsigned short u) {
  return __uint_as_float(((unsigned)u) << 16);
}
static __device__ __forceinline__ unsigned short f2b(float f) {
  __hip_bfloat16 h = __float2bfloat16(f);
  return __builtin_bit_cast(unsigned short, h);
}

// ---------------- CSR build ----------------

__global__ __launch_bounds__(256) void k_zero(int* __restrict__ p, int n) {
  int i = blockIdx.x * 256 + threadIdx.x;
  if (i < n) p[i] = 0;
}

__global__ __launch_bounds__(256) void k_hist(const int* __restrict__ dst, int E, int* __restrict__ deg) {
  int e = blockIdx.x * 256 + threadIdx.x;
  if (e < E) atomicAdd(&deg[dst[e]], 1);
}

__global__ __launch_bounds__(256) void k_scan_a(const int* __restrict__ deg, int N, int NCH,
                                                int* __restrict__ csum) {
  int c = blockIdx.x * 256 + threadIdx.x;
  if (c >= NCH) return;
  int base = c * 256;
  int lim = min(256, N - base);
  int s = 0;
  for (int i = 0; i < lim; ++i) s += deg[base + i];
  csum[c] = s;
}

__global__ __launch_bounds__(512) void k_scan_b(const int* __restrict__ csum, int NCH,
                                                int* __restrict__ coff) {
  __shared__ int buf[512];
  int t = threadIdx.x;
  int v = (t < NCH) ? csum[t] : 0;
  buf[t] = v;
  __syncthreads();
  for (int off = 1; off < 512; off <<= 1) {
    int x = (t >= off) ? buf[t - off] : 0;
    __syncthreads();
    buf[t] += x;
    __syncthreads();
  }
  if (t < NCH) coff[t] = buf[t] - v;
}

__global__ __launch_bounds__(256) void k_scan_c(const int* __restrict__ deg, const int* __restrict__ coff,
                                                int N, int E, int* __restrict__ rowptr,
                                                int* __restrict__ wp) {
  __shared__ int buf[256];
  int c = blockIdx.x, t = threadIdx.x;
  int i = c * 256 + t;
  int v = (i < N) ? deg[i] : 0;
  buf[t] = v;
  __syncthreads();
  for (int off = 1; off < 256; off <<= 1) {
    int x = (t >= off) ? buf[t - off] : 0;
    __syncthreads();
    buf[t] += x;
    __syncthreads();
  }
  if (i < N) {
    int rp = coff[c] + buf[t] - v;
    rowptr[i] = rp;
    wp[i] = rp;
  }
  if (c == 0 && t == 0) rowptr[N] = E;
}

__global__ __launch_bounds__(256) void k_fill(const int* __restrict__ src, const int* __restrict__ dst,
                                              int E, int* __restrict__ wp, int* __restrict__ colsrc) {
  int e = blockIdx.x * 256 + threadIdx.x;
  if (e < E) {
    int p = atomicAdd(&wp[dst[e]], 1);
    colsrc[p] = src[e];
  }
}

// ---------------- weight pack: fp32 [k][n] -> bf16 [n][k] ----------------
// Wp (bf16 elems): [0,16384) lin [128n][128k]; [16384,278528) 4 x [512n][128k]
// (n: 0-127 q, 128-255 k, 256-383 v, 384-511 s); [278528,284672) fc [48n][128k]
// (rows 40-47 zero-padded).

#define PACK_FC   278528
#define PACK_TOT  284672

__global__ __launch_bounds__(256) void k_pack(const float* __restrict__ linW,
                                              const float* __restrict__ Wq, const float* __restrict__ Wk,
                                              const float* __restrict__ Wv, const float* __restrict__ Ws,
                                              const float* __restrict__ fcW,
                                              unsigned short* __restrict__ Wp) {
  int idx = blockIdx.x * 256 + threadIdx.x;
  float val;
  if (idx < 16384) {
    int n = idx >> 7, kk = idx & 127;
    val = linW[kk * 128 + n];
  } else if (idx < PACK_FC) {
    int t = idx - 16384;
    int l = t >> 16, r = t & 65535;
    int n = r >> 7, kk = r & 127;
    int which = n >> 7, nn = n & 127;
    const float* W = (which == 0) ? Wq : (which == 1) ? Wk : (which == 2) ? Wv : Ws;
    val = W[(size_t)l * 16384 + kk * 128 + nn];
  } else if (idx < PACK_TOT) {
    int t = idx - PACK_FC;
    int n = t >> 7, kk = t & 127;
    val = (n < ODIM) ? fcW[kk * ODIM + n] : 0.f;
  } else {
    return;
  }
  Wp[idx] = f2b(val);
}

// ---------------- GEMM lin: hb[N,128] = bf16( x[N,128] @ linW + linb ) ----------------

__global__ __launch_bounds__(256) void k_gemm_lin(const float* __restrict__ x,
                                                  const unsigned short* __restrict__ wl,
                                                  const float* __restrict__ bias,
                                                  unsigned short* __restrict__ hb, int N) {
  __shared__ unsigned short As[32 * LDSA];
  int t = threadIdx.x;
  int rowbase = blockIdx.x * 32;
#pragma unroll
  for (int i = 0; i < 2; ++i) {
    int c = t + i * 256;
    int r = c >> 4, c8 = c & 15;
    int gr = rowbase + r;
    if (gr >= N) gr = N - 1;
    const float4* xp = (const float4*)(x + (size_t)gr * 128 + c8 * 8);
    float4 u0 = xp[0], u1 = xp[1];
    us8 o;
    o[0] = f2b(u0.x); o[1] = f2b(u0.y); o[2] = f2b(u0.z); o[3] = f2b(u0.w);
    o[4] = f2b(u1.x); o[5] = f2b(u1.y); o[6] = f2b(u1.z); o[7] = f2b(u1.w);
    *(us8*)(As + r * LDSA + c8 * 8) = o;
  }
  __syncthreads();

  int lane = t & 63, w = t >> 6;
  int rh = (w & 1) * 16;
  int ch = (w >> 1) * 64;
  int lm = lane & 15, lq = lane >> 4;

  short8 a[4];
#pragma unroll
  for (int ks = 0; ks < 4; ++ks)
    a[ks] = *(const short8*)(As + (rh + lm) * LDSA + ks * 32 + lq * 8);

  f4v acc[4];
#pragma unroll
  for (int ct = 0; ct < 4; ++ct) acc[ct] = (f4v){0.f, 0.f, 0.f, 0.f};

#pragma unroll
  for (int ct = 0; ct < 4; ++ct) {
    const short8* bp = (const short8*)(wl + ((size_t)(ch + ct * 16 + lm)) * 128 + lq * 8);
    short8 b0 = bp[0], b1 = bp[4], b2 = bp[8], b3 = bp[12];
    acc[ct] = __builtin_amdgcn_mfma_f32_16x16x32_bf16(a[0], b0, acc[ct], 0, 0, 0);
    acc[ct] = __builtin_amdgcn_mfma_f32_16x16x32_bf16(a[1], b1, acc[ct], 0, 0, 0);
    acc[ct] = __builtin_amdgcn_mfma_f32_16x16x32_bf16(a[2], b2, acc[ct], 0, 0, 0);
    acc[ct] = __builtin_amdgcn_mfma_f32_16x16x32_bf16(a[3], b3, acc[ct], 0, 0, 0);
  }

#pragma unroll
  for (int ct = 0; ct < 4; ++ct) {
    int c = ch + ct * 16 + lm;
    float bv = bias[c];
#pragma unroll
    for (int r = 0; r < 4; ++r) {
      int row = rowbase + rh + lq * 4 + r;
      if (row < N) hb[(size_t)row * 128 + c] = f2b(acc[ct][r] + bv);
    }
  }
}

// ---------------- GEMM fused qkvs ----------------

__global__ __launch_bounds__(256) void k_gemm_qkvs(const unsigned short* __restrict__ hb,
                                                   const unsigned short* __restrict__ wl,
                                                   const float* __restrict__ bq, const float* __restrict__ bk,
                                                   const float* __restrict__ bv, const float* __restrict__ bs,
                                                   unsigned short* __restrict__ q, unsigned short* __restrict__ k,
                                                   unsigned short* __restrict__ v, float* __restrict__ s, int N) {
  __shared__ unsigned short As[32 * LDSA];
  int t = threadIdx.x;
  int rowbase = blockIdx.x * 32;
#pragma unroll
  for (int i = 0; i < 2; ++i) {
    int c = t + i * 256;
    int r = c >> 4, c8 = c & 15;
    int gr = rowbase + r;
    if (gr >= N) gr = N - 1;
    us8 val = *(const us8*)(hb + (size_t)gr * 128 + c8 * 8);
    *(us8*)(As + r * LDSA + c8 * 8) = val;
  }
  __syncthreads();

  int lane = t & 63, w = t >> 6;
  int rh = (w & 1) * 16;
  int ch = (w >> 1) * 256;
  int lm = lane & 15, lq = lane >> 4;

  short8 a[4];
#pragma unroll
  for (int ks = 0; ks < 4; ++ks)
    a[ks] = *(const short8*)(As + (rh + lm) * LDSA + ks * 32 + lq * 8);

  f4v acc[16];
#pragma unroll
  for (int ct = 0; ct < 16; ++ct) acc[ct] = (f4v){0.f, 0.f, 0.f, 0.f};

#pragma unroll
  for (int ct = 0; ct < 16; ++ct) {
    const short8* bp = (const short8*)(wl + ((size_t)(ch + ct * 16 + lm)) * 128 + lq * 8);
    short8 b0 = bp[0], b1 = bp[4], b2 = bp[8], b3 = bp[12];
    acc[ct] = __builtin_amdgcn_mfma_f32_16x16x32_bf16(a[0], b0, acc[ct], 0, 0, 0);
    acc[ct] = __builtin_amdgcn_mfma_f32_16x16x32_bf16(a[1], b1, acc[ct], 0, 0, 0);
    acc[ct] = __builtin_amdgcn_mfma_f32_16x16x32_bf16(a[2], b2, acc[ct], 0, 0, 0);
    acc[ct] = __builtin_amdgcn_mfma_f32_16x16x32_bf16(a[3], b3, acc[ct], 0, 0, 0);
  }

#pragma unroll
  for (int ct = 0; ct < 16; ++ct) {
    int c = ch + ct * 16 + lm;
    int which = c >> 7, cc = c & 127;
    const float* bsel = (which == 0) ? bq : (which == 1) ? bk : (which == 2) ? bv : bs;
    float bias = bsel[cc];
    unsigned short* obf = (which == 0) ? q : (which == 1) ? k : v;
#pragma unroll
    for (int r = 0; r < 4; ++r) {
      int row = rowbase + rh + lq * 4 + r;
      if (row < N) {
        float val = acc[ct][r] + bias;
        if (which < 3) obf[(size_t)row * 128 + cc] = f2b(val);
        else s[(size_t)row * 128 + cc] = val;
      }
    }
  }
}

// ---------------- attention: one wave/node, two 32-lane edge slots ----------------

__global__ __launch_bounds__(256) void k_attn2(const unsigned short* __restrict__ q,
                                               const unsigned short* __restrict__ kb,
                                               const unsigned short* __restrict__ vb,
                                               const float* __restrict__ s,
                                               const int* __restrict__ rowptr, const int* __restrict__ colsrc,
                                               unsigned short* __restrict__ hb, int n, int do_elu) {
  int wid = blockIdx.x * 4 + (threadIdx.x >> 6);
  if (wid >= n) return;
  int lane = threadIdx.x & 63;
  int half = lane >> 5;
  int d0 = (lane & 31) * 4;
  const float scale = 0.08838834764831844f;  // 1/sqrt(128)

  us4 qu = *(const us4*)(q + (size_t)wid * 128 + d0);
  float q0 = b2f(qu[0]), q1 = b2f(qu[1]), q2 = b2f(qu[2]), q3 = b2f(qu[3]);

  int e0 = rowptr[wid], e1 = rowptr[wid + 1];
  int mid = e0 + ((e1 - e0 + 1) >> 1);
  int lo = half ? mid : e0;
  int hi = half ? e1 : mid;

  float M = -INFINITY, S = 0.f;
  float a0 = 0.f, a1 = 0.f, a2 = 0.f, a3 = 0.f;

  int e = lo;
  for (; e + 1 < hi; e += 2) {
    int j0 = colsrc[e], j1 = colsrc[e + 1];
    us4 k0 = *(const us4*)(kb + (size_t)j0 * 128 + d0);
    us4 k1 = *(const us4*)(kb + (size_t)j1 * 128 + d0);
    us4 v0 = *(const us4*)(vb + (size_t)j0 * 128 + d0);
    us4 v1 = *(const us4*)(vb + (size_t)j1 * 128 + d0);
    float p0 = q0 * b2f(k0[0]) + q1 * b2f(k0[1]) + q2 * b2f(k0[2]) + q3 * b2f(k0[3]);
    float p1 = q0 * b2f(k1[0]) + q1 * b2f(k1[1]) + q2 * b2f(k1[2]) + q3 * b2f(k1[3]);
#pragma unroll
    for (int off = 1; off <= 16; off <<= 1) {
      p0 += __shfl_xor(p0, off, 64);
      p1 += __shfl_xor(p1, off, 64);
    }
    float l0 = p0 * scale, l1 = p1 * scale;
    float newM = fmaxf(M, fmaxf(l0, l1));
    float f = __expf(M - newM);
    float w0 = __expf(l0 - newM), w1 = __expf(l1 - newM);
    S = S * f + w0 + w1;
    a0 = a0 * f + w0 * b2f(v0[0]) + w1 * b2f(v1[0]);
    a1 = a1 * f + w0 * b2f(v0[1]) + w1 * b2f(v1[1]);
    a2 = a2 * f + w0 * b2f(v0[2]) + w1 * b2f(v1[2]);
    a3 = a3 * f + w0 * b2f(v0[3]) + w1 * b2f(v1[3]);
    M = newM;
  }
  if (e < hi) {
    int j0 = colsrc[e];
    us4 k0 = *(const us4*)(kb + (size_t)j0 * 128 + d0);
    us4 v0 = *(const us4*)(vb + (size_t)j0 * 128 + d0);
    float p0 = q0 * b2f(k0[0]) + q1 * b2f(k0[1]) + q2 * b2f(k0[2]) + q3 * b2f(k0[3]);
#pragma unroll
    for (int off = 1; off <= 16; off <<= 1) p0 += __shfl_xor(p0, off, 64);
    float l0 = p0 * scale;
    float newM = fmaxf(M, l0);
    float f = __expf(M - newM);
    float w0 = __expf(l0 - newM);
    S = S * f + w0;
    a0 = a0 * f + w0 * b2f(v0[0]);
    a1 = a1 * f + w0 * b2f(v0[1]);
    a2 = a2 * f + w0 * b2f(v0[2]);
    a3 = a3 * f + w0 * b2f(v0[3]);
    M = newM;
  }

  float Mo = __shfl_xor(M, 32, 64);
  float So = __shfl_xor(S, 32, 64);
  float b0 = __shfl_xor(a0, 32, 64);
  float b1 = __shfl_xor(a1, 32, 64);
  float b2 = __shfl_xor(a2, 32, 64);
  float b3 = __shfl_xor(a3, 32, 64);
  float newM = fmaxf(M, Mo);
  float fs, fo;
  if (newM == -INFINITY) {
    fs = 0.f; fo = 0.f;
  } else {
    fs = __expf(M - newM);
    fo = __expf(Mo - newM);
  }
  S = S * fs + So * fo;
  a0 = a0 * fs + b0 * fo;
  a1 = a1 * fs + b1 * fo;
  a2 = a2 * fs + b2 * fo;
  a3 = a3 * fs + b3 * fo;
  float inv = (S > 0.f) ? 1.f / S : 0.f;

  float4 sk = *(const float4*)(s + (size_t)wid * 128 + d0);
  float o0 = a0 * inv + sk.x;
  float o1 = a1 * inv + sk.y;
  float o2 = a2 * inv + sk.z;
  float o3 = a3 * inv + sk.w;
  if (do_elu) {
    o0 = (o0 > 0.f) ? o0 : (__expf(o0) - 1.f);
    o1 = (o1 > 0.f) ? o1 : (__expf(o1) - 1.f);
    o2 = (o2 > 0.f) ? o2 : (__expf(o2) - 1.f);
    o3 = (o3 > 0.f) ? o3 : (__expf(o3) - 1.f);
  }
  if (half == 0) {
    us4 ov;
    ov[0] = f2b(o0); ov[1] = f2b(o1); ov[2] = f2b(o2); ov[3] = f2b(o3);
    *(us4*)(hb + (size_t)wid * 128 + d0) = ov;
  }
}

// ---------------- MFMA classifier + fused log_softmax ----------------
// block: 256 thr = 4 waves; 64 rows staged in LDS; wave w: rows w*16..w*16+15,
// 48 cols (3 MFMA tiles; cols 40-47 are zero-padded weights, masked in LSM).

__global__ __launch_bounds__(256) void k_fc_mfma(const unsigned short* __restrict__ hb,
                                                 const unsigned short* __restrict__ fcp,  // [48n][128k]
                                                 const float* __restrict__ fcb,
                                                 float* __restrict__ out, int N) {
  __shared__ unsigned short As[64 * LDSA];
  int t = threadIdx.x;
  int rowbase = blockIdx.x * 64;
#pragma unroll
  for (int i = 0; i < 4; ++i) {
    int c = t + i * 256;
    int r = c >> 4, c8 = c & 15;
    int gr = rowbase + r;
    if (gr >= N) gr = N - 1;
    us8 val = *(const us8*)(hb + (size_t)gr * 128 + c8 * 8);
    *(us8*)(As + r * LDSA + c8 * 8) = val;
  }
  __syncthreads();

  int lane = t & 63, w = t >> 6;
  int rh = w * 16;
  int lm = lane & 15, lq = lane >> 4;

  short8 a[4];
#pragma unroll
  for (int ks = 0; ks < 4; ++ks)
    a[ks] = *(const short8*)(As + (rh + lm) * LDSA + ks * 32 + lq * 8);

  f4v acc[3];
#pragma unroll
  for (int ct = 0; ct < 3; ++ct) acc[ct] = (f4v){0.f, 0.f, 0.f, 0.f};

#pragma unroll
  for (int ct = 0; ct < 3; ++ct) {
    const short8* bp = (const short8*)(fcp + ((size_t)(ct * 16 + lm)) * 128 + lq * 8);
    short8 b0 = bp[0], b1 = bp[4], b2 = bp[8], b3 = bp[12];
    acc[ct] = __builtin_amdgcn_mfma_f32_16x16x32_bf16(a[0], b0, acc[ct], 0, 0, 0);
    acc[ct] = __builtin_amdgcn_mfma_f32_16x16x32_bf16(a[1], b1, acc[ct], 0, 0, 0);
    acc[ct] = __builtin_amdgcn_mfma_f32_16x16x32_bf16(a[2], b2, acc[ct], 0, 0, 0);
    acc[ct] = __builtin_amdgcn_mfma_f32_16x16x32_bf16(a[3], b3, acc[ct], 0, 0, 0);
  }

  // biases for this lane's 3 cols (col = ct*16 + lm)
  float bias[3];
#pragma unroll
  for (int ct = 0; ct < 3; ++ct) {
    int c = ct * 16 + lm;
    bias[ct] = (c < ODIM) ? fcb[c] : 0.f;
  }

  // per-row log_softmax: row r's 48 values live on the 16-lane group (3 per lane)
#pragma unroll
  for (int r = 0; r < 4; ++r) {
    float v0 = acc[0][r] + bias[0];
    float v1 = acc[1][r] + bias[1];
    float v2 = (32 + lm < ODIM) ? (acc[2][r] + bias[2]) : -INFINITY;
    float m = fmaxf(fmaxf(v0, v1), v2);
#pragma unroll
    for (int off = 1; off <= 8; off <<= 1) m = fmaxf(m, __shfl_xor(m, off, 64));
    float sum = __expf(v0 - m) + __expf(v1 - m) + ((32 + lm < ODIM) ? __expf(v2 - m) : 0.f);
#pragma unroll
    for (int off = 1; off <= 8; off <<= 1) sum += __shfl_xor(sum, off, 64);
    float lse = m + logf(sum);
    int row = rowbase + rh + lq * 4 + r;
    if (row < N) {
      float* orow = out + (size_t)row * ODIM;
      orow[lm] = v0 - lse;
      orow[16 + lm] = v1 - lse;
      if (32 + lm < ODIM) orow[32 + lm] = v2 - lse;
    }
  }
}

// ---------------- host ----------------

extern "C" void kernel_launch(void* const* d_in, const int* in_sizes, int n_in,
                              void* d_out, int out_size, void* d_ws, size_t ws_size,
                              hipStream_t stream) {
  const float* x    = (const float*)d_in[0];
  const int*   ei   = (const int*)d_in[1];
  const float* linW = (const float*)d_in[2];
  const float* linb = (const float*)d_in[3];
  const float* Wq   = (const float*)d_in[4];
  const float* bq   = (const float*)d_in[5];
  const float* Wk   = (const float*)d_in[6];
  const float* bk   = (const float*)d_in[7];
  const float* Wv   = (const float*)d_in[8];
  const float* bv   = (const float*)d_in[9];
  const float* Wsk  = (const float*)d_in[10];
  const float* bsk  = (const float*)d_in[11];
  const float* fcW  = (const float*)d_in[12];
  const float* fcb  = (const float*)d_in[13];
  float* out = (float*)d_out;

  const int N = in_sizes[0] / HD;
  const int E = in_sizes[1] / 2;
  const int* srcv = ei;
  const int* dstv = ei + E;

  size_t off = 0;
  char* base = (char*)d_ws;
  auto carve = [&](size_t bytes) -> void* {
    void* p = base + off;
    off = (off + bytes + 255) & ~(size_t)255;
    return p;
  };
  unsigned short* Wp = (unsigned short*)carve((size_t)PACK_TOT * 2);
  unsigned short* hb = (unsigned short*)carve((size_t)N * HD * 2);
  unsigned short* qb = (unsigned short*)carve((size_t)N * HD * 2);
  unsigned short* kbuf = (unsigned short*)carve((size_t)N * HD * 2);
  unsigned short* vbuf = (unsigned short*)carve((size_t)N * HD * 2);
  float* sbuf = (float*)carve((size_t)N * HD * 4);
  int* deg    = (int*)carve((size_t)N * 4);
  int* wp     = (int*)carve((size_t)N * 4);
  int* rowptr = (int*)carve((size_t)(N + 1) * 4);
  int* colsrc = (int*)carve((size_t)E * 4);
  int* csum   = (int*)carve(512 * 4);
  int* coff   = (int*)carve(512 * 4);
  (void)ws_size; (void)n_in; (void)out_size;

  const int NCH = (N + 255) / 256;
  dim3 blk(256);
  int eb = (E + 255) / 256;
  int nb = (N + 255) / 256;
  int gx = (N + 31) / 32;
  int wb = (N + 3) / 4;

  // CSR by dst
  k_zero<<<nb, blk, 0, stream>>>(deg, N);
  k_hist<<<eb, blk, 0, stream>>>(dstv, E, deg);
  k_scan_a<<<(NCH + 255) / 256, blk, 0, stream>>>(deg, N, NCH, csum);
  k_scan_b<<<1, 512, 0, stream>>>(csum, NCH, coff);
  k_scan_c<<<NCH, blk, 0, stream>>>(deg, coff, N, E, rowptr, wp);
  k_fill<<<eb, blk, 0, stream>>>(srcv, dstv, E, wp, colsrc);

  // weight pack
  k_pack<<<(PACK_TOT + 255) / 256, blk, 0, stream>>>(linW, Wq, Wk, Wv, Wsk, fcW, Wp);

  // input projection
  k_gemm_lin<<<gx, blk, 0, stream>>>(x, Wp, linb, hb, N);

  // layers
  for (int l = 0; l < 4; ++l) {
    const unsigned short* wl = Wp + 16384 + (size_t)l * 65536;
    k_gemm_qkvs<<<gx, blk, 0, stream>>>(hb, wl, bq + l * HD, bk + l * HD, bv + l * HD, bsk + l * HD,
                                        qb, kbuf, vbuf, sbuf, N);
    k_attn2<<<wb, blk, 0, stream>>>(qb, kbuf, vbuf, sbuf, rowptr, colsrc, hb, N, (l < 3) ? 1 : 0);
  }

  // classifier + fused log_softmax
  k_fc_mfma<<<(N + 63) / 64, blk, 0, stream>>>(hb, Wp + PACK_FC, fcb, out, N);
}

// Round 4
// 1160.000 us; speedup vs baseline: 2.1200x; 1.2425x over previous
//
#include <hip/hip_runtime.h>
#include <hip/hip_bf16.h>
#include <math.h>

// ---------------------------------------------------------------------------
// DeepGT round 3:
//  - qkvs GEMM: one tensor per wave (32rx128c), 2x MFMA:B-load ratio, outputs
//    staged via LDS -> coalesced us8 stores (was 64 scalar 2B stores/thread).
//  - attn: 4x16-lane edge slots, us8 gathers, 4-step reduce, guarded merges.
//  - lin GEMM: LDS-staged coalesced store epilogue.
// ---------------------------------------------------------------------------

#define HD 128
#define ODIM 40
#define LDSA 136  // padded LDS row stride (bf16 elems)

typedef __attribute__((ext_vector_type(8))) short short8;
typedef __attribute__((ext_vector_type(4))) float f4v;
typedef __attribute__((ext_vector_type(4))) unsigned short us4;
typedef __attribute__((ext_vector_type(8))) unsigned short us8;

static __device__ __forceinline__ float b2f(unsigned short u) {
  return __uint_as_float(((unsigned)u) << 16);
}
static __device__ __forceinline__ unsigned short f2b(float f) {
  __hip_bfloat16 h = __float2bfloat16(f);
  return __builtin_bit_cast(unsigned short, h);
}

// ---------------- CSR build ----------------

__global__ __launch_bounds__(256) void k_zero(int* __restrict__ p, int n) {
  int i = blockIdx.x * 256 + threadIdx.x;
  if (i < n) p[i] = 0;
}

__global__ __launch_bounds__(256) void k_hist(const int* __restrict__ dst, int E, int* __restrict__ deg) {
  int e = blockIdx.x * 256 + threadIdx.x;
  if (e < E) atomicAdd(&deg[dst[e]], 1);
}

__global__ __launch_bounds__(256) void k_scan_a(const int* __restrict__ deg, int N, int NCH,
                                                int* __restrict__ csum) {
  int c = blockIdx.x * 256 + threadIdx.x;
  if (c >= NCH) return;
  int base = c * 256;
  int lim = min(256, N - base);
  int s = 0;
  for (int i = 0; i < lim; ++i) s += deg[base + i];
  csum[c] = s;
}

__global__ __launch_bounds__(512) void k_scan_b(const int* __restrict__ csum, int NCH,
                                                int* __restrict__ coff) {
  __shared__ int buf[512];
  int t = threadIdx.x;
  int v = (t < NCH) ? csum[t] : 0;
  buf[t] = v;
  __syncthreads();
  for (int off = 1; off < 512; off <<= 1) {
    int x = (t >= off) ? buf[t - off] : 0;
    __syncthreads();
    buf[t] += x;
    __syncthreads();
  }
  if (t < NCH) coff[t] = buf[t] - v;
}

__global__ __launch_bounds__(256) void k_scan_c(const int* __restrict__ deg, const int* __restrict__ coff,
                                                int N, int E, int* __restrict__ rowptr,
                                                int* __restrict__ wp) {
  __shared__ int buf[256];
  int c = blockIdx.x, t = threadIdx.x;
  int i = c * 256 + t;
  int v = (i < N) ? deg[i] : 0;
  buf[t] = v;
  __syncthreads();
  for (int off = 1; off < 256; off <<= 1) {
    int x = (t >= off) ? buf[t - off] : 0;
    __syncthreads();
    buf[t] += x;
    __syncthreads();
  }
  if (i < N) {
    int rp = coff[c] + buf[t] - v;
    rowptr[i] = rp;
    wp[i] = rp;
  }
  if (c == 0 && t == 0) rowptr[N] = E;
}

__global__ __launch_bounds__(256) void k_fill(const int* __restrict__ src, const int* __restrict__ dst,
                                              int E, int* __restrict__ wp, int* __restrict__ colsrc) {
  int e = blockIdx.x * 256 + threadIdx.x;
  if (e < E) {
    int p = atomicAdd(&wp[dst[e]], 1);
    colsrc[p] = src[e];
  }
}

// ---------------- weight pack: fp32 [k][n] -> bf16 [n][k] ----------------
// Wp (bf16 elems): [0,16384) lin [128n][128k]; [16384,278528) 4 x [512n][128k]
// (n: 0-127 q, 128-255 k, 256-383 v, 384-511 s); [278528,284672) fc [48n][128k]
// (rows 40-47 zero-padded).

#define PACK_FC   278528
#define PACK_TOT  284672

__global__ __launch_bounds__(256) void k_pack(const float* __restrict__ linW,
                                              const float* __restrict__ Wq, const float* __restrict__ Wk,
                                              const float* __restrict__ Wv, const float* __restrict__ Ws,
                                              const float* __restrict__ fcW,
                                              unsigned short* __restrict__ Wp) {
  int idx = blockIdx.x * 256 + threadIdx.x;
  float val;
  if (idx < 16384) {
    int n = idx >> 7, kk = idx & 127;
    val = linW[kk * 128 + n];
  } else if (idx < PACK_FC) {
    int t = idx - 16384;
    int l = t >> 16, r = t & 65535;
    int n = r >> 7, kk = r & 127;
    int which = n >> 7, nn = n & 127;
    const float* W = (which == 0) ? Wq : (which == 1) ? Wk : (which == 2) ? Wv : Ws;
    val = W[(size_t)l * 16384 + kk * 128 + nn];
  } else if (idx < PACK_TOT) {
    int t = idx - PACK_FC;
    int n = t >> 7, kk = t & 127;
    val = (n < ODIM) ? fcW[kk * ODIM + n] : 0.f;
  } else {
    return;
  }
  Wp[idx] = f2b(val);
}

// ---------------- GEMM lin: hb[N,128] = bf16( x[N,128] @ linW + linb ) ----------------
// 4 waves, 32 rows; wave: 16r x 64c; LDS-staged coalesced store epilogue.

__global__ __launch_bounds__(256) void k_gemm_lin(const float* __restrict__ x,
                                                  const unsigned short* __restrict__ wl,
                                                  const float* __restrict__ bias,
                                                  unsigned short* __restrict__ hb, int N) {
  __shared__ unsigned short As[32 * LDSA];  // also reused as 32x128 output stage
  int t = threadIdx.x;
  int rowbase = blockIdx.x * 32;
#pragma unroll
  for (int i = 0; i < 2; ++i) {
    int c = t + i * 256;
    int r = c >> 4, c8 = c & 15;
    int gr = rowbase + r;
    if (gr >= N) gr = N - 1;
    const float4* xp = (const float4*)(x + (size_t)gr * 128 + c8 * 8);
    float4 u0 = xp[0], u1 = xp[1];
    us8 o;
    o[0] = f2b(u0.x); o[1] = f2b(u0.y); o[2] = f2b(u0.z); o[3] = f2b(u0.w);
    o[4] = f2b(u1.x); o[5] = f2b(u1.y); o[6] = f2b(u1.z); o[7] = f2b(u1.w);
    *(us8*)(As + r * LDSA + c8 * 8) = o;
  }
  __syncthreads();

  int lane = t & 63, w = t >> 6;
  int rh = (w & 1) * 16;
  int ch = (w >> 1) * 64;
  int lm = lane & 15, lq = lane >> 4;

  short8 a[4];
#pragma unroll
  for (int ks = 0; ks < 4; ++ks)
    a[ks] = *(const short8*)(As + (rh + lm) * LDSA + ks * 32 + lq * 8);
  __syncthreads();  // As free after this

  f4v acc[4];
#pragma unroll
  for (int ct = 0; ct < 4; ++ct) acc[ct] = (f4v){0.f, 0.f, 0.f, 0.f};

#pragma unroll
  for (int ct = 0; ct < 4; ++ct) {
    const short8* bp = (const short8*)(wl + ((size_t)(ch + ct * 16 + lm)) * 128 + lq * 8);
    short8 b0 = bp[0], b1 = bp[4], b2 = bp[8], b3 = bp[12];
    acc[ct] = __builtin_amdgcn_mfma_f32_16x16x32_bf16(a[0], b0, acc[ct], 0, 0, 0);
    acc[ct] = __builtin_amdgcn_mfma_f32_16x16x32_bf16(a[1], b1, acc[ct], 0, 0, 0);
    acc[ct] = __builtin_amdgcn_mfma_f32_16x16x32_bf16(a[2], b2, acc[ct], 0, 0, 0);
    acc[ct] = __builtin_amdgcn_mfma_f32_16x16x32_bf16(a[3], b3, acc[ct], 0, 0, 0);
  }

  unsigned short* stage = As;  // 32 rows x 128 cols, stride 128
#pragma unroll
  for (int ct = 0; ct < 4; ++ct) {
    int c = ch + ct * 16 + lm;
    float bv = bias[c];
#pragma unroll
    for (int r = 0; r < 4; ++r)
      stage[(rh + lq * 4 + r) * 128 + c] = f2b(acc[ct][r] + bv);
  }
  __syncthreads();
#pragma unroll
  for (int i = 0; i < 2; ++i) {
    int c = t + i * 256;
    int r = c >> 4, c8 = c & 15;
    int row = rowbase + r;
    if (row < N)
      *(us8*)(hb + (size_t)row * 128 + c8 * 8) = *(const us8*)(stage + r * 128 + c8 * 8);
  }
}

// ---------------- GEMM fused qkvs: wave w computes tensor w (32r x 128c) ----------------

__global__ __launch_bounds__(256, 3) void k_gemm_qkvs(const unsigned short* __restrict__ hb,
                                                      const unsigned short* __restrict__ wl,  // [512n][128k]
                                                      const float* __restrict__ bq, const float* __restrict__ bk,
                                                      const float* __restrict__ bv, const float* __restrict__ bs,
                                                      unsigned short* __restrict__ q, unsigned short* __restrict__ k,
                                                      unsigned short* __restrict__ v, float* __restrict__ s, int N) {
  __shared__ unsigned short As[32 * LDSA];  // A stage; reused as 32x128 output stage
  int t = threadIdx.x;
  int rowbase = blockIdx.x * 32;
#pragma unroll
  for (int i = 0; i < 2; ++i) {
    int c = t + i * 256;
    int r = c >> 4, c8 = c & 15;
    int gr = rowbase + r;
    if (gr >= N) gr = N - 1;
    *(us8*)(As + r * LDSA + c8 * 8) = *(const us8*)(hb + (size_t)gr * 128 + c8 * 8);
  }
  __syncthreads();

  int lane = t & 63, w = t >> 6;   // w = tensor: 0 q, 1 k, 2 v, 3 s
  int lm = lane & 15, lq = lane >> 4;

  // A fragments for all 32 rows (2 row-tiles), shared shape across waves
  short8 a[2][4];
#pragma unroll
  for (int rt = 0; rt < 2; ++rt)
#pragma unroll
    for (int ks = 0; ks < 4; ++ks)
      a[rt][ks] = *(const short8*)(As + (rt * 16 + lm) * LDSA + ks * 32 + lq * 8);
  __syncthreads();  // As free after this

  f4v acc[2][8];
#pragma unroll
  for (int rt = 0; rt < 2; ++rt)
#pragma unroll
    for (int ct = 0; ct < 8; ++ct) acc[rt][ct] = (f4v){0.f, 0.f, 0.f, 0.f};

  const unsigned short* wb = wl + (size_t)w * 16384;  // this tensor's [128n][128k]
#pragma unroll
  for (int ct = 0; ct < 8; ++ct) {
    const short8* bp = (const short8*)(wb + (size_t)(ct * 16 + lm) * 128 + lq * 8);
    short8 b0 = bp[0], b1 = bp[4], b2 = bp[8], b3 = bp[12];
#pragma unroll
    for (int rt = 0; rt < 2; ++rt) {
      acc[rt][ct] = __builtin_amdgcn_mfma_f32_16x16x32_bf16(a[rt][0], b0, acc[rt][ct], 0, 0, 0);
      acc[rt][ct] = __builtin_amdgcn_mfma_f32_16x16x32_bf16(a[rt][1], b1, acc[rt][ct], 0, 0, 0);
      acc[rt][ct] = __builtin_amdgcn_mfma_f32_16x16x32_bf16(a[rt][2], b2, acc[rt][ct], 0, 0, 0);
      acc[rt][ct] = __builtin_amdgcn_mfma_f32_16x16x32_bf16(a[rt][3], b3, acc[rt][ct], 0, 0, 0);
    }
  }

  const float* bsel = (w == 0) ? bq : (w == 1) ? bk : (w == 2) ? bv : bs;
  float bias[8];
#pragma unroll
  for (int ct = 0; ct < 8; ++ct) bias[ct] = bsel[ct * 16 + lm];

  // s: direct fp32 stores (64B segments per quarter-wave)
  if (w == 3) {
#pragma unroll
    for (int rt = 0; rt < 2; ++rt)
#pragma unroll
      for (int ct = 0; ct < 8; ++ct)
#pragma unroll
        for (int r = 0; r < 4; ++r) {
          int row = rowbase + rt * 16 + lq * 4 + r;
          if (row < N) s[(size_t)row * 128 + ct * 16 + lm] = acc[rt][ct][r] + bias[ct];
        }
  }

  // q/k/v: stage via LDS, coalesced us8 stores by all 256 threads
  unsigned short* stage = As;  // 32x128, stride 128
  for (int p = 0; p < 3; ++p) {
    if (w == p) {
#pragma unroll
      for (int rt = 0; rt < 2; ++rt)
#pragma unroll
        for (int ct = 0; ct < 8; ++ct)
#pragma unroll
          for (int r = 0; r < 4; ++r)
            stage[(rt * 16 + lq * 4 + r) * 128 + ct * 16 + lm] = f2b(acc[rt][ct][r] + bias[ct]);
    }
    __syncthreads();
    unsigned short* outp = (p == 0) ? q : (p == 1) ? k : v;
#pragma unroll
    for (int i = 0; i < 2; ++i) {
      int c = t + i * 256;
      int r = c >> 4, c8 = c & 15;
      int row = rowbase + r;
      if (row < N)
        *(us8*)(outp + (size_t)row * 128 + c8 * 8) = *(const us8*)(stage + r * 128 + c8 * 8);
    }
    __syncthreads();
  }
}

// ---------------- attention: one wave/node, four 16-lane edge slots ----------------
// lane: slot=lane>>4 (edge-list quarter), lm=lane&15 holds dims lm*8..lm*8+7.
// us8 (16B) gathers; 4-step shuffle reduce; guarded 2-stage slot merge.

__global__ __launch_bounds__(256) void k_attn3(const unsigned short* __restrict__ q,
                                               const unsigned short* __restrict__ kb,
                                               const unsigned short* __restrict__ vb,
                                               const float* __restrict__ s,
                                               const int* __restrict__ rowptr, const int* __restrict__ colsrc,
                                               unsigned short* __restrict__ hb, int n, int do_elu) {
  int wid = blockIdx.x * 4 + (threadIdx.x >> 6);
  if (wid >= n) return;
  int lane = threadIdx.x & 63;
  int slot = lane >> 4;
  int lm = lane & 15;
  int d0 = lm * 8;
  const float scale = 0.08838834764831844f;  // 1/sqrt(128)

  us8 qu = *(const us8*)(q + (size_t)wid * 128 + d0);
  float qf[8];
#pragma unroll
  for (int i = 0; i < 8; ++i) qf[i] = b2f(qu[i]);

  int e0 = rowptr[wid], e1 = rowptr[wid + 1];
  int deg = e1 - e0;
  int cbase = deg >> 2, rem = deg & 3;
  int lo = e0 + slot * cbase + min(slot, rem);
  int hi = lo + cbase + (slot < rem ? 1 : 0);

  float M = -INFINITY, S = 0.f;
  float acc[8];
#pragma unroll
  for (int i = 0; i < 8; ++i) acc[i] = 0.f;

  int e = lo;
  for (; e + 1 < hi; e += 2) {
    int j0 = colsrc[e], j1 = colsrc[e + 1];
    us8 k0 = *(const us8*)(kb + (size_t)j0 * 128 + d0);
    us8 k1 = *(const us8*)(kb + (size_t)j1 * 128 + d0);
    us8 v0 = *(const us8*)(vb + (size_t)j0 * 128 + d0);
    us8 v1 = *(const us8*)(vb + (size_t)j1 * 128 + d0);
    float p0 = 0.f, p1 = 0.f;
#pragma unroll
    for (int i = 0; i < 8; ++i) {
      p0 = fmaf(qf[i], b2f(k0[i]), p0);
      p1 = fmaf(qf[i], b2f(k1[i]), p1);
    }
#pragma unroll
    for (int off = 1; off <= 8; off <<= 1) {
      p0 += __shfl_xor(p0, off, 64);
      p1 += __shfl_xor(p1, off, 64);
    }
    float l0 = p0 * scale, l1 = p1 * scale;
    float newM = fmaxf(M, fmaxf(l0, l1));
    float f = __expf(M - newM);
    float w0 = __expf(l0 - newM), w1 = __expf(l1 - newM);
    S = S * f + w0 + w1;
#pragma unroll
    for (int i = 0; i < 8; ++i)
      acc[i] = fmaf(acc[i], f, fmaf(w0, b2f(v0[i]), w1 * b2f(v1[i])));
    M = newM;
  }
  if (e < hi) {
    int j0 = colsrc[e];
    us8 k0 = *(const us8*)(kb + (size_t)j0 * 128 + d0);
    us8 v0 = *(const us8*)(vb + (size_t)j0 * 128 + d0);
    float p0 = 0.f;
#pragma unroll
    for (int i = 0; i < 8; ++i) p0 = fmaf(qf[i], b2f(k0[i]), p0);
#pragma unroll
    for (int off = 1; off <= 8; off <<= 1) p0 += __shfl_xor(p0, off, 64);
    float l0 = p0 * scale;
    float newM = fmaxf(M, l0);
    float f = __expf(M - newM);
    float w0 = __expf(l0 - newM);
    S = S * f + w0;
#pragma unroll
    for (int i = 0; i < 8; ++i) acc[i] = fmaf(acc[i], f, w0 * b2f(v0[i]));
    M = newM;
  }

  // merge 4 slots (xor 16, then xor 32), guarded for empty (-inf) states
#pragma unroll
  for (int off = 16; off <= 32; off <<= 1) {
    float Mo = __shfl_xor(M, off, 64);
    float So = __shfl_xor(S, off, 64);
    float bo[8];
#pragma unroll
    for (int i = 0; i < 8; ++i) bo[i] = __shfl_xor(acc[i], off, 64);
    float newM = fmaxf(M, Mo);
    float fs, fo;
    if (newM == -INFINITY) {
      fs = 0.f; fo = 0.f;
    } else {
      fs = __expf(M - newM);
      fo = __expf(Mo - newM);
    }
    S = S * fs + So * fo;
#pragma unroll
    for (int i = 0; i < 8; ++i) acc[i] = acc[i] * fs + bo[i] * fo;
    M = newM;
  }

  if (slot == 0) {
    float inv = (S > 0.f) ? 1.f / S : 0.f;
    const float4* sp = (const float4*)(s + (size_t)wid * 128 + d0);
    float4 s0 = sp[0], s1 = sp[1];
    float o[8];
    o[0] = acc[0] * inv + s0.x; o[1] = acc[1] * inv + s0.y;
    o[2] = acc[2] * inv + s0.z; o[3] = acc[3] * inv + s0.w;
    o[4] = acc[4] * inv + s1.x; o[5] = acc[5] * inv + s1.y;
    o[6] = acc[6] * inv + s1.z; o[7] = acc[7] * inv + s1.w;
    us8 ov;
#pragma unroll
    for (int i = 0; i < 8; ++i) {
      float x = o[i];
      if (do_elu) x = (x > 0.f) ? x : (__expf(x) - 1.f);
      ov[i] = f2b(x);
    }
    *(us8*)(hb + (size_t)wid * 128 + d0) = ov;
  }
}

// ---------------- MFMA classifier + fused log_softmax ----------------

__global__ __launch_bounds__(256) void k_fc_mfma(const unsigned short* __restrict__ hb,
                                                 const unsigned short* __restrict__ fcp,  // [48n][128k]
                                                 const float* __restrict__ fcb,
                                                 float* __restrict__ out, int N) {
  __shared__ unsigned short As[64 * LDSA];
  int t = threadIdx.x;
  int rowbase = blockIdx.x * 64;
#pragma unroll
  for (int i = 0; i < 4; ++i) {
    int c = t + i * 256;
    int r = c >> 4, c8 = c & 15;
    int gr = rowbase + r;
    if (gr >= N) gr = N - 1;
    us8 val = *(const us8*)(hb + (size_t)gr * 128 + c8 * 8);
    *(us8*)(As + r * LDSA + c8 * 8) = val;
  }
  __syncthreads();

  int lane = t & 63, w = t >> 6;
  int rh = w * 16;
  int lm = lane & 15, lq = lane >> 4;

  short8 a[4];
#pragma unroll
  for (int ks = 0; ks < 4; ++ks)
    a[ks] = *(const short8*)(As + (rh + lm) * LDSA + ks * 32 + lq * 8);

  f4v acc[3];
#pragma unroll
  for (int ct = 0; ct < 3; ++ct) acc[ct] = (f4v){0.f, 0.f, 0.f, 0.f};

#pragma unroll
  for (int ct = 0; ct < 3; ++ct) {
    const short8* bp = (const short8*)(fcp + ((size_t)(ct * 16 + lm)) * 128 + lq * 8);
    short8 b0 = bp[0], b1 = bp[4], b2 = bp[8], b3 = bp[12];
    acc[ct] = __builtin_amdgcn_mfma_f32_16x16x32_bf16(a[0], b0, acc[ct], 0, 0, 0);
    acc[ct] = __builtin_amdgcn_mfma_f32_16x16x32_bf16(a[1], b1, acc[ct], 0, 0, 0);
    acc[ct] = __builtin_amdgcn_mfma_f32_16x16x32_bf16(a[2], b2, acc[ct], 0, 0, 0);
    acc[ct] = __builtin_amdgcn_mfma_f32_16x16x32_bf16(a[3], b3, acc[ct], 0, 0, 0);
  }

  float bias[3];
#pragma unroll
  for (int ct = 0; ct < 3; ++ct) {
    int c = ct * 16 + lm;
    bias[ct] = (c < ODIM) ? fcb[c] : 0.f;
  }

#pragma unroll
  for (int r = 0; r < 4; ++r) {
    float v0 = acc[0][r] + bias[0];
    float v1 = acc[1][r] + bias[1];
    float v2 = (32 + lm < ODIM) ? (acc[2][r] + bias[2]) : -INFINITY;
    float m = fmaxf(fmaxf(v0, v1), v2);
#pragma unroll
    for (int off = 1; off <= 8; off <<= 1) m = fmaxf(m, __shfl_xor(m, off, 64));
    float sum = __expf(v0 - m) + __expf(v1 - m) + ((32 + lm < ODIM) ? __expf(v2 - m) : 0.f);
#pragma unroll
    for (int off = 1; off <= 8; off <<= 1) sum += __shfl_xor(sum, off, 64);
    float lse = m + logf(sum);
    int row = rowbase + rh + lq * 4 + r;
    if (row < N) {
      float* orow = out + (size_t)row * ODIM;
      orow[lm] = v0 - lse;
      orow[16 + lm] = v1 - lse;
      if (32 + lm < ODIM) orow[32 + lm] = v2 - lse;
    }
  }
}

// ---------------- host ----------------

extern "C" void kernel_launch(void* const* d_in, const int* in_sizes, int n_in,
                              void* d_out, int out_size, void* d_ws, size_t ws_size,
                              hipStream_t stream) {
  const float* x    = (const float*)d_in[0];
  const int*   ei   = (const int*)d_in[1];
  const float* linW = (const float*)d_in[2];
  const float* linb = (const float*)d_in[3];
  const float* Wq   = (const float*)d_in[4];
  const float* bq   = (const float*)d_in[5];
  const float* Wk   = (const float*)d_in[6];
  const float* bk   = (const float*)d_in[7];
  const float* Wv   = (const float*)d_in[8];
  const float* bv   = (const float*)d_in[9];
  const float* Wsk  = (const float*)d_in[10];
  const float* bsk  = (const float*)d_in[11];
  const float* fcW  = (const float*)d_in[12];
  const float* fcb  = (const float*)d_in[13];
  float* out = (float*)d_out;

  const int N = in_sizes[0] / HD;
  const int E = in_sizes[1] / 2;
  const int* srcv = ei;
  const int* dstv = ei + E;

  size_t off = 0;
  char* base = (char*)d_ws;
  auto carve = [&](size_t bytes) -> void* {
    void* p = base + off;
    off = (off + bytes + 255) & ~(size_t)255;
    return p;
  };
  unsigned short* Wp = (unsigned short*)carve((size_t)PACK_TOT * 2);
  unsigned short* hb = (unsigned short*)carve((size_t)N * HD * 2);
  unsigned short* qb = (unsigned short*)carve((size_t)N * HD * 2);
  unsigned short* kbuf = (unsigned short*)carve((size_t)N * HD * 2);
  unsigned short* vbuf = (unsigned short*)carve((size_t)N * HD * 2);
  float* sbuf = (float*)carve((size_t)N * HD * 4);
  int* deg    = (int*)carve((size_t)N * 4);
  int* wp     = (int*)carve((size_t)N * 4);
  int* rowptr = (int*)carve((size_t)(N + 1) * 4);
  int* colsrc = (int*)carve((size_t)E * 4);
  int* csum   = (int*)carve(512 * 4);
  int* coff   = (int*)carve(512 * 4);
  (void)ws_size; (void)n_in; (void)out_size;

  const int NCH = (N + 255) / 256;
  dim3 blk(256);
  int eb = (E + 255) / 256;
  int nb = (N + 255) / 256;
  int gx = (N + 31) / 32;
  int wb = (N + 3) / 4;

  // CSR by dst
  k_zero<<<nb, blk, 0, stream>>>(deg, N);
  k_hist<<<eb, blk, 0, stream>>>(dstv, E, deg);
  k_scan_a<<<(NCH + 255) / 256, blk, 0, stream>>>(deg, N, NCH, csum);
  k_scan_b<<<1, 512, 0, stream>>>(csum, NCH, coff);
  k_scan_c<<<NCH, blk, 0, stream>>>(deg, coff, N, E, rowptr, wp);
  k_fill<<<eb, blk, 0, stream>>>(srcv, dstv, E, wp, colsrc);

  // weight pack
  k_pack<<<(PACK_TOT + 255) / 256, blk, 0, stream>>>(linW, Wq, Wk, Wv, Wsk, fcW, Wp);

  // input projection
  k_gemm_lin<<<gx, blk, 0, stream>>>(x, Wp, linb, hb, N);

  // layers
  for (int l = 0; l < 4; ++l) {
    const unsigned short* wl = Wp + 16384 + (size_t)l * 65536;
    k_gemm_qkvs<<<gx, blk, 0, stream>>>(hb, wl, bq + l * HD, bk + l * HD, bv + l * HD, bsk + l * HD,
                                        qb, kbuf, vbuf, sbuf, N);
    k_attn3<<<wb, blk, 0, stream>>>(qb, kbuf, vbuf, sbuf, rowptr, colsrc, hb, N, (l < 3) ? 1 : 0);
  }

  // classifier + fused log_softmax
  k_fc_mfma<<<(N + 63) / 64, blk, 0, stream>>>(hb, Wp + PACK_FC, fcb, out, N);
}